// Round 1
// baseline (799.879 us; speedup 1.0000x reference)
//
#include <hip/hip_runtime.h>
#include <hip/hip_bf16.h>

typedef __bf16 bf16_t;
typedef __attribute__((ext_vector_type(8))) __bf16 bf16x8;
typedef __attribute__((ext_vector_type(4))) float f32x4;

#define FD 1024
#define HD 256
#define GG 4096
#define MTILE 128

// ---------------------------------------------------------------------------
// prep: w1t = ce_w1^T (fp32, for coalesced CE dot); w2t/w3t = bf16 N-major
// ---------------------------------------------------------------------------
__global__ __launch_bounds__(256) void prep_kernel(
    const float* __restrict__ ce_w1,   // [1024,256]
    const float* __restrict__ sf_w2,   // [256,256]
    const float* __restrict__ sf_w3,   // [256,128]
    float* __restrict__ w1t,           // [256,1024]  (may be null)
    bf16_t* __restrict__ w2t,          // [256 n][256 k]
    bf16_t* __restrict__ w3t)          // [128 n][256 k]
{
    int id = blockIdx.x * 256 + threadIdx.x;   // 0..262143
    if (w1t != nullptr) {
        int j = id >> 10, k = id & 1023;
        w1t[id] = ce_w1[k * 256 + j];
    }
    if (id < 65536) {
        int n = id >> 8, k = id & 255;
        w2t[id] = (bf16_t)sf_w2[k * 256 + n];
    }
    if (id < 32768) {
        int n = id >> 8, k = id & 255;
        w3t[id] = (bf16_t)sf_w3[k * 128 + n];
    }
}

// ---------------------------------------------------------------------------
// context encoder: one block per batch row; fp32 throughout.
// zpart[b][j] = z_c[b] @ sf_w1[2:] + sf_b1   (bias folded in)
// ---------------------------------------------------------------------------
__global__ __launch_bounds__(256) void ce_kernel(
    const float* __restrict__ features,   // [256,1024]
    const float* __restrict__ ce_w1,      // [1024,256] (fallback path)
    const float* __restrict__ w1t,        // [256,1024] or null
    const float* __restrict__ ce_b1,
    const float* __restrict__ ce_w2, const float* __restrict__ ce_b2,
    const float* __restrict__ ce_w3, const float* __restrict__ ce_b3,
    const float* __restrict__ sf_w1,      // [66,256]
    const float* __restrict__ sf_b1,
    float* __restrict__ zpart)            // [256,256]
{
    __shared__ float fs[FD];
    __shared__ float z1[HD];
    __shared__ float z2[HD / 2];
    __shared__ float zc[64];
    const int b = blockIdx.x, t = threadIdx.x;

    #pragma unroll
    for (int i = 0; i < 4; ++i) fs[t + i * 256] = features[b * FD + t + i * 256];
    __syncthreads();

    // layer 1: 1024 -> 256
    {
        float s = ce_b1[t];
        if (w1t != nullptr) {
            const float4* wr = reinterpret_cast<const float4*>(w1t + t * FD);
            #pragma unroll 4
            for (int k = 0; k < FD / 4; ++k) {
                float4 w = wr[k];
                const float4 f = *reinterpret_cast<const float4*>(&fs[k * 4]);
                s = fmaf(w.x, f.x, s);
                s = fmaf(w.y, f.y, s);
                s = fmaf(w.z, f.z, s);
                s = fmaf(w.w, f.w, s);
            }
        } else {
            #pragma unroll 8
            for (int k = 0; k < FD; ++k) s = fmaf(fs[k], ce_w1[k * 256 + t], s);
        }
        z1[t] = s > 0.f ? s : 0.f;
    }
    __syncthreads();

    // layer 2: 256 -> 128
    if (t < 128) {
        float s = ce_b2[t];
        #pragma unroll 8
        for (int k = 0; k < 256; ++k) s = fmaf(z1[k], ce_w2[k * 128 + t], s);
        z2[t] = s > 0.f ? s : 0.f;
    }
    __syncthreads();

    // layer 3: 128 -> 64 (no relu)
    if (t < 64) {
        float s = ce_b3[t];
        #pragma unroll 8
        for (int k = 0; k < 128; ++k) s = fmaf(z2[k], ce_w3[k * 64 + t], s);
        zc[t] = s;
    }
    __syncthreads();

    // zpart = zc @ sf_w1[2:] + sf_b1
    {
        float s = sf_b1[t];
        #pragma unroll 8
        for (int k = 0; k < 64; ++k) s = fmaf(zc[k], sf_w1[(2 + k) * 256 + t], s);
        zpart[b * HD + t] = s;
    }
}

// ---------------------------------------------------------------------------
// fused field MLP: per block = (batch b, 128-coord tile)
//   h1 = relu(coords @ sf_w1[:2] + zpart[b])          -> LDS bf16 [128][256]
//   h2 = relu(h1 @ w2 + b2)                           -> LDS bf16 [128][256]
//   h3 = relu(h2 @ w3 + b3); out = sigmoid(h3@w4+b4)  -> registers
// LDS XOR-swizzle at 16B-chunk granularity: chunk ^= (row&7)  (G4 / T2)
// ---------------------------------------------------------------------------
__global__ __launch_bounds__(512, 2) void field_kernel(
    const float* __restrict__ coords,   // [4096,2]
    const float* __restrict__ sf_w1,    // [66,256] rows 0,1 used
    const float* __restrict__ zpart,    // [256,256]
    const bf16_t* __restrict__ w2t,     // [256 n][256 k]
    const float* __restrict__ sf_b2,    // [256]
    const bf16_t* __restrict__ w3t,     // [128 n][256 k]
    const float* __restrict__ sf_b3,    // [128]
    const float* __restrict__ sf_w4,    // [128]
    const float* __restrict__ sf_b4,    // [1]
    float* __restrict__ out)            // [256,4096]
{
    __shared__ __attribute__((aligned(128))) bf16_t hs[MTILE * HD];  // 64 KB

    const int bid = blockIdx.x;
    const int b = bid >> 5;          // batch
    const int gbase = (bid & 31) * MTILE;
    const int tid = threadIdx.x;
    const int wid = tid >> 6;
    const int lane = tid & 63;
    const int l15 = lane & 15;
    const int l4 = lane >> 4;

    // ---- build h1 into LDS (bf16, swizzled) ----
    // 4096 chunks of 8 cols; each thread writes 8 chunks
    #pragma unroll
    for (int it = 0; it < 8; ++it) {
        int c = it * 512 + tid;          // 0..4095
        int row = c >> 5;
        int kc = c & 31;                 // 16B chunk within row
        int g = gbase + row;
        float x0 = coords[2 * g], x1 = coords[2 * g + 1];
        const f32x4* zp4 = reinterpret_cast<const f32x4*>(zpart + b * HD + kc * 8);
        const f32x4* wa4 = reinterpret_cast<const f32x4*>(sf_w1 + kc * 8);
        const f32x4* wb4 = reinterpret_cast<const f32x4*>(sf_w1 + HD + kc * 8);
        bf16x8 v;
        #pragma unroll
        for (int h = 0; h < 2; ++h) {
            f32x4 z = zp4[h], wa = wa4[h], wb = wb4[h];
            #pragma unroll
            for (int j = 0; j < 4; ++j) {
                float s = fmaf(x0, wa[j], fmaf(x1, wb[j], z[j]));
                v[h * 4 + j] = (bf16_t)(s > 0.f ? s : 0.f);
            }
        }
        *reinterpret_cast<bf16x8*>(&hs[(row * 32 + (kc ^ (row & 7))) * 8]) = v;
    }
    __syncthreads();

    // ---- GEMM1: h2 = relu(h1 @ w2 + b2); wave tiling 2M x 4N (64 rows x 64 cols) ----
    const int wm = wid >> 2, wn = wid & 3;
    f32x4 acc[4][4] = {};
    for (int ks = 0; ks < 8; ++ks) {
        bf16x8 af[4], bfr[4];
        #pragma unroll
        for (int m = 0; m < 4; ++m) {
            int row = wm * 64 + m * 16 + l15;
            int kc = ks * 4 + l4;
            af[m] = *reinterpret_cast<const bf16x8*>(&hs[(row * 32 + (kc ^ (row & 7))) * 8]);
        }
        #pragma unroll
        for (int n = 0; n < 4; ++n) {
            int col = wn * 64 + n * 16 + l15;
            bfr[n] = *reinterpret_cast<const bf16x8*>(&w2t[col * 256 + ks * 32 + l4 * 8]);
        }
        #pragma unroll
        for (int m = 0; m < 4; ++m)
            #pragma unroll
            for (int n = 0; n < 4; ++n)
                acc[m][n] = __builtin_amdgcn_mfma_f32_16x16x32_bf16(af[m], bfr[n], acc[m][n], 0, 0, 0);
    }
    __syncthreads();   // all reads of h1 done

    // epilogue: write h2 (bf16) over hs, swizzled
    #pragma unroll
    for (int m = 0; m < 4; ++m) {
        #pragma unroll
        for (int n = 0; n < 4; ++n) {
            int col = wn * 64 + n * 16 + l15;
            float bb = sf_b2[col];
            #pragma unroll
            for (int i = 0; i < 4; ++i) {
                int row = wm * 64 + m * 16 + l4 * 4 + i;
                float v = acc[m][n][i] + bb;
                v = v > 0.f ? v : 0.f;
                hs[row * 256 + (col ^ ((row & 7) << 3))] = (bf16_t)v;
            }
        }
    }
    __syncthreads();

    // ---- GEMM2: 8M x 1N (wave owns 16 rows, all 128 cols) + fused final dot ----
    f32x4 acc2[8] = {};
    for (int ks = 0; ks < 8; ++ks) {
        int row = wid * 16 + l15;
        int kc = ks * 4 + l4;
        bf16x8 a = *reinterpret_cast<const bf16x8*>(&hs[(row * 32 + (kc ^ (row & 7))) * 8]);
        #pragma unroll
        for (int n = 0; n < 8; ++n) {
            bf16x8 bb = *reinterpret_cast<const bf16x8*>(&w3t[(n * 16 + l15) * 256 + ks * 32 + l4 * 8]);
            acc2[n] = __builtin_amdgcn_mfma_f32_16x16x32_bf16(a, bb, acc2[n], 0, 0, 0);
        }
    }

    // h3 = relu(acc2 + b3); logits = h3 @ w4 + b4; sigmoid
    float p[4] = {0.f, 0.f, 0.f, 0.f};
    #pragma unroll
    for (int n = 0; n < 8; ++n) {
        int col = n * 16 + l15;
        float b3 = sf_b3[col];
        float w4 = sf_w4[col];
        #pragma unroll
        for (int i = 0; i < 4; ++i) {
            float v = acc2[n][i] + b3;
            v = v > 0.f ? v : 0.f;
            p[i] = fmaf(v, w4, p[i]);
        }
    }
    #pragma unroll
    for (int m = 1; m < 16; m <<= 1) {
        #pragma unroll
        for (int i = 0; i < 4; ++i) p[i] += __shfl_xor(p[i], m, 64);
    }
    if (l15 == 0) {
        float b4 = sf_b4[0];
        float4 o;
        float* po = &o.x;
        #pragma unroll
        for (int i = 0; i < 4; ++i) {
            float logit = p[i] + b4;
            po[i] = 1.f / (1.f + __expf(-logit));
        }
        *reinterpret_cast<float4*>(out + b * GG + gbase + wid * 16 + l4 * 4) = o;
    }
}

// ---------------------------------------------------------------------------
extern "C" void kernel_launch(void* const* d_in, const int* in_sizes, int n_in,
                              void* d_out, int out_size, void* d_ws, size_t ws_size,
                              hipStream_t stream)
{
    const float* features = (const float*)d_in[0];
    const float* coords   = (const float*)d_in[1];
    const float* ce_w1 = (const float*)d_in[2];
    const float* ce_b1 = (const float*)d_in[3];
    const float* ce_w2 = (const float*)d_in[4];
    const float* ce_b2 = (const float*)d_in[5];
    const float* ce_w3 = (const float*)d_in[6];
    const float* ce_b3 = (const float*)d_in[7];
    const float* sf_w1 = (const float*)d_in[8];
    const float* sf_b1 = (const float*)d_in[9];
    const float* sf_w2 = (const float*)d_in[10];
    const float* sf_b2 = (const float*)d_in[11];
    const float* sf_w3 = (const float*)d_in[12];
    const float* sf_b3 = (const float*)d_in[13];
    const float* sf_w4 = (const float*)d_in[14];
    const float* sf_b4 = (const float*)d_in[15];
    float* out = (float*)d_out;

    char* ws = (char*)d_ws;
    float*  zpart = (float*)ws;                                  // 256 KB
    bf16_t* w2t   = (bf16_t*)(ws + 65536 * 4);                   // 128 KB
    bf16_t* w3t   = (bf16_t*)(ws + 65536 * 4 + 65536 * 2);       //  64 KB
    float*  w1t   = (float*)(ws + 65536 * 4 + 65536 * 2 + 32768 * 2); // 1 MB (optional)
    const size_t need_w1t = (size_t)(65536 * 4 + 65536 * 2 + 32768 * 2) + (size_t)FD * HD * 4;
    float* w1t_ptr = (ws_size >= need_w1t) ? w1t : nullptr;

    hipLaunchKernelGGL(prep_kernel, dim3(1024), dim3(256), 0, stream,
                       ce_w1, sf_w2, sf_w3, w1t_ptr, w2t, w3t);
    hipLaunchKernelGGL(ce_kernel, dim3(256), dim3(256), 0, stream,
                       features, ce_w1, w1t_ptr, ce_b1, ce_w2, ce_b2, ce_w3, ce_b3,
                       sf_w1, sf_b1, zpart);
    hipLaunchKernelGGL(field_kernel, dim3(8192), dim3(512), 0, stream,
                       coords, sf_w1, zpart, w2t, sf_b2, w3t, sf_b3, sf_w4, sf_b4, out);
}

// Round 2
// 312.520 us; speedup vs baseline: 2.5595x; 2.5595x over previous
//
#include <hip/hip_runtime.h>
#include <hip/hip_bf16.h>

typedef __bf16 bf16_t;
typedef __attribute__((ext_vector_type(8))) __bf16 bf16x8;
typedef __attribute__((ext_vector_type(4))) float f32x4;

#define FD 1024
#define HD 256
#define GG 4096

// ---------------------------------------------------------------------------
// prep: w1t = ce_w1^T (fp32, for coalesced CE dot); w2t/w3t = bf16 N-major
// ---------------------------------------------------------------------------
__global__ __launch_bounds__(256) void prep_kernel(
    const float* __restrict__ ce_w1,   // [1024,256]
    const float* __restrict__ sf_w2,   // [256,256]
    const float* __restrict__ sf_w3,   // [256,128]
    float* __restrict__ w1t,           // [256,1024]  (may be null)
    bf16_t* __restrict__ w2t,          // [256 n][256 k]
    bf16_t* __restrict__ w3t)          // [128 n][256 k]
{
    int id = blockIdx.x * 256 + threadIdx.x;   // 0..262143
    if (w1t != nullptr) {
        int j = id >> 10, k = id & 1023;
        w1t[id] = ce_w1[k * 256 + j];
    }
    if (id < 65536) {
        int n = id >> 8, k = id & 255;
        w2t[id] = (bf16_t)sf_w2[k * 256 + n];
    }
    if (id < 32768) {
        int n = id >> 8, k = id & 255;
        w3t[id] = (bf16_t)sf_w3[k * 128 + n];
    }
}

// ---------------------------------------------------------------------------
// context encoder: one block per batch row; fp32 throughout.
// zpart[b][j] = z_c[b] @ sf_w1[2:] + sf_b1   (bias folded in)
// ---------------------------------------------------------------------------
__global__ __launch_bounds__(256) void ce_kernel(
    const float* __restrict__ features,   // [256,1024]
    const float* __restrict__ ce_w1,      // [1024,256] (fallback path)
    const float* __restrict__ w1t,        // [256,1024] or null
    const float* __restrict__ ce_b1,
    const float* __restrict__ ce_w2, const float* __restrict__ ce_b2,
    const float* __restrict__ ce_w3, const float* __restrict__ ce_b3,
    const float* __restrict__ sf_w1,      // [66,256]
    const float* __restrict__ sf_b1,
    float* __restrict__ zpart)            // [256,256]
{
    __shared__ float fs[FD];
    __shared__ float z1[HD];
    __shared__ float z2[HD / 2];
    __shared__ float zc[64];
    const int b = blockIdx.x, t = threadIdx.x;

    #pragma unroll
    for (int i = 0; i < 4; ++i) fs[t + i * 256] = features[b * FD + t + i * 256];
    __syncthreads();

    // layer 1: 1024 -> 256
    {
        float s = ce_b1[t];
        if (w1t != nullptr) {
            const float4* wr = reinterpret_cast<const float4*>(w1t + t * FD);
            #pragma unroll 4
            for (int k = 0; k < FD / 4; ++k) {
                float4 w = wr[k];
                const float4 f = *reinterpret_cast<const float4*>(&fs[k * 4]);
                s = fmaf(w.x, f.x, s);
                s = fmaf(w.y, f.y, s);
                s = fmaf(w.z, f.z, s);
                s = fmaf(w.w, f.w, s);
            }
        } else {
            #pragma unroll 8
            for (int k = 0; k < FD; ++k) s = fmaf(fs[k], ce_w1[k * 256 + t], s);
        }
        z1[t] = s > 0.f ? s : 0.f;
    }
    __syncthreads();

    // layer 2: 256 -> 128
    if (t < 128) {
        float s = ce_b2[t];
        #pragma unroll 8
        for (int k = 0; k < 256; ++k) s = fmaf(z1[k], ce_w2[k * 128 + t], s);
        z2[t] = s > 0.f ? s : 0.f;
    }
    __syncthreads();

    // layer 3: 128 -> 64 (no relu)
    if (t < 64) {
        float s = ce_b3[t];
        #pragma unroll 8
        for (int k = 0; k < 128; ++k) s = fmaf(z2[k], ce_w3[k * 64 + t], s);
        zc[t] = s;
    }
    __syncthreads();

    // zpart = zc @ sf_w1[2:] + sf_b1
    {
        float s = sf_b1[t];
        #pragma unroll 8
        for (int k = 0; k < 64; ++k) s = fmaf(zc[k], sf_w1[(2 + k) * 256 + t], s);
        zpart[b * HD + t] = s;
    }
}

// ---------------------------------------------------------------------------
// fused field MLP, weight-stationary: one block per batch element (grid=256,
// 1 block/CU, 8 waves, 2 waves/SIMD, VGPR cap 256 via launch_bounds).
//
// Per block: loop over 64 tiles of 64 coords.
//   h1 tile (LDS, double-buffered, bf16, 16B-chunk XOR swizzle)
//   GEMM1: A=h1 from LDS, B=w2t slice RESIDENT IN REGISTERS (64 VGPR/wave)
//   h2 tile -> LDS
//   GEMM2 swapped: D=h3^T = mfma(A=w3t slice in regs, B=h2 from LDS)
//     -> lane holds h3[one row][8 cols] -> fused w4 dot + shfl reduce
//   tiny LDS partial reduce (4 col-groups) -> sigmoid -> store
// ---------------------------------------------------------------------------
__global__ __launch_bounds__(512, 2) void field_kernel(
    const float* __restrict__ coords,   // [4096,2]
    const float* __restrict__ sf_w1,    // [66,256] rows 0,1 used
    const float* __restrict__ zpart,    // [256,256]
    const bf16_t* __restrict__ w2t,     // [256 n][256 k]
    const float* __restrict__ sf_b2,    // [256]
    const bf16_t* __restrict__ w3t,     // [128 n][256 k]
    const float* __restrict__ sf_b3,    // [128]
    const float* __restrict__ sf_w4,    // [128]
    const float* __restrict__ sf_b4,    // [1]
    float* __restrict__ out)            // [256,4096]
{
    __shared__ __attribute__((aligned(128))) bf16_t h1[2][64 * 256];  // 2x32KB
    __shared__ __attribute__((aligned(128))) bf16_t h2[64 * 256];     // 32KB
    __shared__ float partials[4][64];                                 // 1KB

    const int b = blockIdx.x;
    const int tid = threadIdx.x;
    const int wid = tid >> 6;
    const int lane = tid & 63;
    const int l15 = lane & 15;
    const int l4 = lane >> 4;

    // ---- resident weights ----
    // GEMM1 B-frags: wave wid owns cols wid*32 .. wid*32+31  (64 VGPRs)
    bf16x8 b1f[8][2];
    #pragma unroll
    for (int ks = 0; ks < 8; ++ks)
        #pragma unroll
        for (int n = 0; n < 2; ++n)
            b1f[ks][n] = *reinterpret_cast<const bf16x8*>(
                &w2t[(wid * 32 + n * 16 + l15) * 256 + ks * 32 + l4 * 8]);

    // GEMM2 A-frags (swapped): wave covers w3 cols cgrp*32 .. +31, rows rhalf*32 .. +31
    const int cgrp = wid & 3, rhalf = wid >> 2;
    bf16x8 w3f[8][2];
    #pragma unroll
    for (int ks = 0; ks < 8; ++ks)
        #pragma unroll
        for (int cb = 0; cb < 2; ++cb)
            w3f[ks][cb] = *reinterpret_cast<const bf16x8*>(
                &w3t[(cgrp * 32 + cb * 16 + l15) * 256 + ks * 32 + l4 * 8]);

    float b2r[2];
    #pragma unroll
    for (int n = 0; n < 2; ++n) b2r[n] = sf_b2[wid * 32 + n * 16 + l15];
    float b3r[2][4], w4r[2][4];
    #pragma unroll
    for (int cb = 0; cb < 2; ++cb)
        #pragma unroll
        for (int i = 0; i < 4; ++i) {
            int c = cgrp * 32 + cb * 16 + l4 * 4 + i;
            b3r[cb][i] = sf_b3[c];
            w4r[cb][i] = sf_w4[c];
        }
    const float b4v = sf_b4[0];

    // ---- resident h1-build constants: this thread always builds chunk kc ----
    const int kc = tid & 31;       // 16B chunk (8 cols) within a row
    const int rbase = tid >> 5;    // row offset 0..15
    f32x4 zp[2], wa[2], wb[2];
    #pragma unroll
    for (int h = 0; h < 2; ++h) {
        zp[h] = *reinterpret_cast<const f32x4*>(&zpart[b * HD + kc * 8 + h * 4]);
        wa[h] = *reinterpret_cast<const f32x4*>(&sf_w1[kc * 8 + h * 4]);
        wb[h] = *reinterpret_cast<const f32x4*>(&sf_w1[HD + kc * 8 + h * 4]);
    }

    // build tile t's h1 rows for this thread into buf
    auto build = [&](int t, bf16_t* buf) {
        const int g0 = t * 64;
        #pragma unroll
        for (int it = 0; it < 4; ++it) {
            int row = it * 16 + rbase;
            float2 xy = *reinterpret_cast<const float2*>(&coords[2 * (g0 + row)]);
            bf16x8 v;
            #pragma unroll
            for (int h = 0; h < 2; ++h) {
                #pragma unroll
                for (int j = 0; j < 4; ++j) {
                    float s = fmaf(xy.x, wa[h][j], fmaf(xy.y, wb[h][j], zp[h][j]));
                    v[h * 4 + j] = (bf16_t)(s > 0.f ? s : 0.f);
                }
            }
            *reinterpret_cast<bf16x8*>(&buf[row * 256 + ((kc ^ (row & 7)) << 3)]) = v;
        }
    };

    // prologue: tile 0
    build(0, h1[0]);
    __syncthreads();

    #pragma unroll 1
    for (int t = 0; t < 64; ++t) {
        const bf16_t* cur = h1[t & 1];
        bf16_t* nxt = h1[(t + 1) & 1];

        // ---- GEMM1: acc1[m][n], rows m*16+l15, cols wid*32+n*16+l15 ----
        f32x4 acc1[4][2] = {};
        #pragma unroll
        for (int ks = 0; ks < 8; ++ks) {
            bf16x8 a[4];
            #pragma unroll
            for (int m = 0; m < 4; ++m) {
                int row = m * 16 + l15;
                int ch = (ks * 4 + l4) ^ (row & 7);
                a[m] = *reinterpret_cast<const bf16x8*>(&cur[row * 256 + (ch << 3)]);
            }
            #pragma unroll
            for (int m = 0; m < 4; ++m)
                #pragma unroll
                for (int n = 0; n < 2; ++n)
                    acc1[m][n] = __builtin_amdgcn_mfma_f32_16x16x32_bf16(a[m], b1f[ks][n], acc1[m][n], 0, 0, 0);
        }

        // ---- build next tile's h1 (overlaps with surrounding compute) ----
        if (t + 1 < 64) build(t + 1, nxt);

        // ---- epilogue: h2 = relu(acc1 + b2) -> LDS (swizzled row-major) ----
        #pragma unroll
        for (int m = 0; m < 4; ++m) {
            #pragma unroll
            for (int n = 0; n < 2; ++n) {
                int col = wid * 32 + n * 16 + l15;
                #pragma unroll
                for (int i = 0; i < 4; ++i) {
                    int row = m * 16 + l4 * 4 + i;
                    float v = acc1[m][n][i] + b2r[n];
                    v = v > 0.f ? v : 0.f;
                    h2[row * 256 + ((((col >> 3) ^ (row & 7)) << 3) | (col & 7))] = (bf16_t)v;
                }
            }
        }
        __syncthreads();   // h2 ready (also orders next-h1 writes before next reads)

        // ---- GEMM2 (swapped): acc2[rblk][cb] = h3^T tile ----
        f32x4 acc2[2][2] = {};
        #pragma unroll
        for (int ks = 0; ks < 8; ++ks) {
            bf16x8 hb[2];
            #pragma unroll
            for (int rb = 0; rb < 2; ++rb) {
                int row = rhalf * 32 + rb * 16 + l15;
                int ch = (ks * 4 + l4) ^ (row & 7);
                hb[rb] = *reinterpret_cast<const bf16x8*>(&h2[row * 256 + (ch << 3)]);
            }
            #pragma unroll
            for (int rb = 0; rb < 2; ++rb)
                #pragma unroll
                for (int cb = 0; cb < 2; ++cb)
                    acc2[rb][cb] = __builtin_amdgcn_mfma_f32_16x16x32_bf16(w3f[ks][cb], hb[rb], acc2[rb][cb], 0, 0, 0);
        }

        // h3 = relu(acc2 + b3); partial logit dot with w4; reduce over l4 groups
        float p[2] = {0.f, 0.f};
        #pragma unroll
        for (int rb = 0; rb < 2; ++rb)
            #pragma unroll
            for (int cb = 0; cb < 2; ++cb)
                #pragma unroll
                for (int i = 0; i < 4; ++i) {
                    float v = acc2[rb][cb][i] + b3r[cb][i];
                    v = v > 0.f ? v : 0.f;
                    p[rb] = fmaf(v, w4r[cb][i], p[rb]);
                }
        #pragma unroll
        for (int rb = 0; rb < 2; ++rb) {
            p[rb] += __shfl_xor(p[rb], 16, 64);
            p[rb] += __shfl_xor(p[rb], 32, 64);
        }
        if (l4 == 0) {
            partials[cgrp][rhalf * 32 + l15] = p[0];
            partials[cgrp][rhalf * 32 + 16 + l15] = p[1];
        }
        __syncthreads();   // partials ready

        // ---- final: sum 4 col-group partials, sigmoid, store ----
        if (tid < 64) {
            float s = partials[0][tid] + partials[1][tid] + partials[2][tid] + partials[3][tid] + b4v;
            out[b * GG + t * 64 + tid] = 1.f / (1.f + __expf(-s));
        }
    }
}

// ---------------------------------------------------------------------------
extern "C" void kernel_launch(void* const* d_in, const int* in_sizes, int n_in,
                              void* d_out, int out_size, void* d_ws, size_t ws_size,
                              hipStream_t stream)
{
    const float* features = (const float*)d_in[0];
    const float* coords   = (const float*)d_in[1];
    const float* ce_w1 = (const float*)d_in[2];
    const float* ce_b1 = (const float*)d_in[3];
    const float* ce_w2 = (const float*)d_in[4];
    const float* ce_b2 = (const float*)d_in[5];
    const float* ce_w3 = (const float*)d_in[6];
    const float* ce_b3 = (const float*)d_in[7];
    const float* sf_w1 = (const float*)d_in[8];
    const float* sf_b1 = (const float*)d_in[9];
    const float* sf_w2 = (const float*)d_in[10];
    const float* sf_b2 = (const float*)d_in[11];
    const float* sf_w3 = (const float*)d_in[12];
    const float* sf_b3 = (const float*)d_in[13];
    const float* sf_w4 = (const float*)d_in[14];
    const float* sf_b4 = (const float*)d_in[15];
    float* out = (float*)d_out;

    char* ws = (char*)d_ws;
    float*  zpart = (float*)ws;                                  // 256 KB
    bf16_t* w2t   = (bf16_t*)(ws + 65536 * 4);                   // 128 KB
    bf16_t* w3t   = (bf16_t*)(ws + 65536 * 4 + 65536 * 2);       //  64 KB
    float*  w1t   = (float*)(ws + 65536 * 4 + 65536 * 2 + 32768 * 2); // 1 MB (optional)
    const size_t need_w1t = (size_t)(65536 * 4 + 65536 * 2 + 32768 * 2) + (size_t)FD * HD * 4;
    float* w1t_ptr = (ws_size >= need_w1t) ? w1t : nullptr;

    hipLaunchKernelGGL(prep_kernel, dim3(1024), dim3(256), 0, stream,
                       ce_w1, sf_w2, sf_w3, w1t_ptr, w2t, w3t);
    hipLaunchKernelGGL(ce_kernel, dim3(256), dim3(256), 0, stream,
                       features, ce_w1, w1t_ptr, ce_b1, ce_w2, ce_b2, ce_w3, ce_b3,
                       sf_w1, sf_b1, zpart);
    hipLaunchKernelGGL(field_kernel, dim3(256), dim3(512), 0, stream,
                       coords, sf_w1, zpart, w2t, sf_b2, w3t, sf_b3, sf_w4, sf_b4, out);
}

// Round 3
// 272.231 us; speedup vs baseline: 2.9382x; 1.1480x over previous
//
#include <hip/hip_runtime.h>
#include <hip/hip_bf16.h>

typedef __bf16 bf16_t;
typedef __attribute__((ext_vector_type(8))) __bf16 bf16x8;
typedef __attribute__((ext_vector_type(4))) __bf16 bf16x4;
typedef __attribute__((ext_vector_type(4))) float f32x4;

#define FD 1024
#define HD 256
#define GG 4096

// ---------------------------------------------------------------------------
// prep: w1t = ce_w1^T (fp32, coalesced CE dot); w2t/w3t = bf16 N-major
// ---------------------------------------------------------------------------
__global__ __launch_bounds__(256) void prep_kernel(
    const float* __restrict__ ce_w1,   // [1024,256]
    const float* __restrict__ sf_w2,   // [256,256]
    const float* __restrict__ sf_w3,   // [256,128]
    float* __restrict__ w1t,           // [256,1024]  (may be null)
    bf16_t* __restrict__ w2t,          // [256 n][256 k]
    bf16_t* __restrict__ w3t)          // [128 n][256 k]
{
    int id = blockIdx.x * 256 + threadIdx.x;   // 0..262143
    if (w1t != nullptr) {
        int j = id >> 10, k = id & 1023;
        w1t[id] = ce_w1[k * 256 + j];
    }
    if (id < 65536) {
        int n = id >> 8, k = id & 255;
        w2t[id] = (bf16_t)sf_w2[k * 256 + n];
    }
    if (id < 32768) {
        int n = id >> 8, k = id & 255;
        w3t[id] = (bf16_t)sf_w3[k * 128 + n];
    }
}

// ---------------------------------------------------------------------------
// context encoder: one block per batch row; fp32 throughout.
// zpart[b][j] = z_c[b] @ sf_w1[2:] + sf_b1   (bias folded in)
// ---------------------------------------------------------------------------
__global__ __launch_bounds__(256) void ce_kernel(
    const float* __restrict__ features,   // [256,1024]
    const float* __restrict__ ce_w1,      // [1024,256] (fallback path)
    const float* __restrict__ w1t,        // [256,1024] or null
    const float* __restrict__ ce_b1,
    const float* __restrict__ ce_w2, const float* __restrict__ ce_b2,
    const float* __restrict__ ce_w3, const float* __restrict__ ce_b3,
    const float* __restrict__ sf_w1,      // [66,256]
    const float* __restrict__ sf_b1,
    float* __restrict__ zpart)            // [256,256]
{
    __shared__ float fs[FD];
    __shared__ float z1[HD];
    __shared__ float z2[HD / 2];
    __shared__ float zc[64];
    const int b = blockIdx.x, t = threadIdx.x;

    #pragma unroll
    for (int i = 0; i < 4; ++i) fs[t + i * 256] = features[b * FD + t + i * 256];
    __syncthreads();

    // layer 1: 1024 -> 256
    {
        float s = ce_b1[t];
        if (w1t != nullptr) {
            const float4* wr = reinterpret_cast<const float4*>(w1t + t * FD);
            #pragma unroll 4
            for (int k = 0; k < FD / 4; ++k) {
                float4 w = wr[k];
                const float4 f = *reinterpret_cast<const float4*>(&fs[k * 4]);
                s = fmaf(w.x, f.x, s);
                s = fmaf(w.y, f.y, s);
                s = fmaf(w.z, f.z, s);
                s = fmaf(w.w, f.w, s);
            }
        } else {
            #pragma unroll 8
            for (int k = 0; k < FD; ++k) s = fmaf(fs[k], ce_w1[k * 256 + t], s);
        }
        z1[t] = s > 0.f ? s : 0.f;
    }
    __syncthreads();

    // layer 2: 256 -> 128
    if (t < 128) {
        float s = ce_b2[t];
        #pragma unroll 8
        for (int k = 0; k < 256; ++k) s = fmaf(z1[k], ce_w2[k * 128 + t], s);
        z2[t] = s > 0.f ? s : 0.f;
    }
    __syncthreads();

    // layer 3: 128 -> 64 (no relu)
    if (t < 64) {
        float s = ce_b3[t];
        #pragma unroll 8
        for (int k = 0; k < 128; ++k) s = fmaf(z2[k], ce_w3[k * 64 + t], s);
        zc[t] = s;
    }
    __syncthreads();

    // zpart = zc @ sf_w1[2:] + sf_b1
    {
        float s = sf_b1[t];
        #pragma unroll 8
        for (int k = 0; k < 64; ++k) s = fmaf(zc[k], sf_w1[(2 + k) * 256 + t], s);
        zpart[b * HD + t] = s;
    }
}

// ---------------------------------------------------------------------------
// fused field MLP, weight-stationary, SWAPPED GEMM1 (vector epilogue):
//   grid=256 (1 block/CU), 512 thr (8 waves).
//   Per tile (64 coords):
//     GEMM1: acc = mfma(A=w2t frags resident in regs, B=h1 frag from LDS)
//            -> lane holds h2[row][4 consecutive cols] -> ds_write_b64 x8
//     GEMM2: acc2 = mfma(A=w3t frags resident, B=h2 frag from LDS) = h3^T
//            -> fused relu + w4-dot -> per-lane k-group partial -> LDS
//     final: one wave sums 16 k-group partials, sigmoid, store (overlaps
//            next tile's GEMM1; no extra barrier)
//   2 barriers/tile; h1 double-buffered; coords loads issued early.
// ---------------------------------------------------------------------------
__global__ __launch_bounds__(512, 2) void field_kernel(
    const float* __restrict__ coords,   // [4096,2]
    const float* __restrict__ sf_w1,    // [66,256] rows 0,1 used
    const float* __restrict__ zpart,    // [256,256]
    const bf16_t* __restrict__ w2t,     // [256 n][256 k]
    const float* __restrict__ sf_b2,    // [256]
    const bf16_t* __restrict__ w3t,     // [128 n][256 k]
    const float* __restrict__ sf_b3,    // [128]
    const float* __restrict__ sf_w4,    // [128]
    const float* __restrict__ sf_b4,    // [1]
    float* __restrict__ out)            // [256,4096]
{
    __shared__ __attribute__((aligned(128))) bf16_t h1[2][64 * 256];  // 2x32KB
    __shared__ __attribute__((aligned(128))) bf16_t h2[64 * 256];     // 32KB
    __shared__ float partials[64][20];                                // 5KB padded

    const int b = blockIdx.x;
    const int tid = threadIdx.x;
    const int wid = tid >> 6;
    const int lane = tid & 63;
    const int l15 = lane & 15;
    const int l4 = lane >> 4;

    // ---- resident weights ----
    // GEMM1 A-frags (w2^T): wave wid owns h2 cols wid*32 .. +31 (64 VGPR)
    bf16x8 b1f[8][2];
    #pragma unroll
    for (int ks = 0; ks < 8; ++ks)
        #pragma unroll
        for (int n = 0; n < 2; ++n)
            b1f[ks][n] = *reinterpret_cast<const bf16x8*>(
                &w2t[(wid * 32 + n * 16 + l15) * 256 + ks * 32 + l4 * 8]);

    // GEMM2 A-frags (w3^T): wave covers w3 cols cgrp*32..+31, h2 rows rhalf*32..+31
    const int cgrp = wid & 3, rhalf = wid >> 2;
    bf16x8 w3f[8][2];
    #pragma unroll
    for (int ks = 0; ks < 8; ++ks)
        #pragma unroll
        for (int cb = 0; cb < 2; ++cb)
            w3f[ks][cb] = *reinterpret_cast<const bf16x8*>(
                &w3t[(cgrp * 32 + cb * 16 + l15) * 256 + ks * 32 + l4 * 8]);

    const float b4v = sf_b4[0];

    // ---- resident h1-build constants: thread always builds chunk kc ----
    const int kc = tid & 31;       // 16B chunk (8 cols) within a row
    const int rbase = tid >> 5;    // row offset 0..15
    f32x4 zp[2], wa[2], wb[2];
    #pragma unroll
    for (int h = 0; h < 2; ++h) {
        zp[h] = *reinterpret_cast<const f32x4*>(&zpart[b * HD + kc * 8 + h * 4]);
        wa[h] = *reinterpret_cast<const f32x4*>(&sf_w1[kc * 8 + h * 4]);
        wb[h] = *reinterpret_cast<const f32x4*>(&sf_w1[HD + kc * 8 + h * 4]);
    }

    // compute+write h1 rows for this thread into buf, given preloaded coords
    auto build_store = [&](const float2* xy, bf16_t* buf) {
        #pragma unroll
        for (int it = 0; it < 4; ++it) {
            int row = it * 16 + rbase;
            bf16x8 v;
            #pragma unroll
            for (int h = 0; h < 2; ++h) {
                #pragma unroll
                for (int j = 0; j < 4; ++j) {
                    float s = fmaf(xy[it].x, wa[h][j], fmaf(xy[it].y, wb[h][j], zp[h][j]));
                    v[h * 4 + j] = (bf16_t)(s > 0.f ? s : 0.f);
                }
            }
            *reinterpret_cast<bf16x8*>(&buf[row * 256 + ((kc ^ (row & 7)) << 3)]) = v;
        }
    };

    // prologue: tile 0
    {
        float2 xy0[4];
        #pragma unroll
        for (int it = 0; it < 4; ++it)
            xy0[it] = *reinterpret_cast<const float2*>(&coords[2 * (it * 16 + rbase)]);
        build_store(xy0, h1[0]);
    }
    __syncthreads();

    #pragma unroll 1
    for (int t = 0; t < 64; ++t) {
        const bf16_t* cur = h1[t & 1];
        bf16_t* nxt = h1[(t + 1) & 1];

        // ---- issue next tile's coords loads EARLY (hide under GEMM1) ----
        float2 xy[4];
        if (t + 1 < 64) {
            #pragma unroll
            for (int it = 0; it < 4; ++it)
                xy[it] = *reinterpret_cast<const float2*>(
                    &coords[2 * ((t + 1) * 64 + it * 16 + rbase)]);
        }

        // ---- GEMM1 (swapped): acc1s[m][n] = h2^T tile ----
        // lane: h2[row=m*16+l15][col=wid*32+n*16+l4*4+r]
        f32x4 acc1s[4][2] = {};
        #pragma unroll
        for (int ks = 0; ks < 8; ++ks) {
            bf16x8 a[4];
            #pragma unroll
            for (int m = 0; m < 4; ++m) {
                int row = m * 16 + l15;
                int ch = (ks * 4 + l4) ^ (row & 7);
                a[m] = *reinterpret_cast<const bf16x8*>(&cur[row * 256 + (ch << 3)]);
            }
            __builtin_amdgcn_s_setprio(1);
            #pragma unroll
            for (int m = 0; m < 4; ++m)
                #pragma unroll
                for (int n = 0; n < 2; ++n)
                    acc1s[m][n] = __builtin_amdgcn_mfma_f32_16x16x32_bf16(b1f[ks][n], a[m], acc1s[m][n], 0, 0, 0);
            __builtin_amdgcn_s_setprio(0);
        }

        // ---- build next tile's h1 (VALU; overlaps with MFMA drain) ----
        if (t + 1 < 64) build_store(xy, nxt);

        // ---- epilogue: h2 = relu(acc1s + b2) -> LDS, vectorized b64 writes ----
        {
            #pragma unroll
            for (int n = 0; n < 2; ++n) {
                f32x4 b2v = *reinterpret_cast<const f32x4*>(&sf_b2[wid * 32 + n * 16 + l4 * 4]);
                #pragma unroll
                for (int m = 0; m < 4; ++m) {
                    int row = m * 16 + l15;
                    int chunk = wid * 4 + n * 2 + (l4 >> 1);
                    bf16x4 v;
                    #pragma unroll
                    for (int r = 0; r < 4; ++r) {
                        float x = acc1s[m][n][r] + b2v[r];
                        v[r] = (bf16_t)(x > 0.f ? x : 0.f);
                    }
                    *reinterpret_cast<bf16x4*>(
                        &h2[row * 256 + ((chunk ^ (row & 7)) << 3) + (l4 & 1) * 4]) = v;
                }
            }
        }
        __syncthreads();   // h2 ready; h1[nxt] writes ordered

        // ---- GEMM2 (swapped): acc2[rb][cb] = h3^T tile ----
        f32x4 acc2[2][2] = {};
        #pragma unroll
        for (int ks = 0; ks < 8; ++ks) {
            bf16x8 hb[2];
            #pragma unroll
            for (int rb = 0; rb < 2; ++rb) {
                int row = rhalf * 32 + rb * 16 + l15;
                int ch = (ks * 4 + l4) ^ (row & 7);
                hb[rb] = *reinterpret_cast<const bf16x8*>(&h2[row * 256 + (ch << 3)]);
            }
            __builtin_amdgcn_s_setprio(1);
            #pragma unroll
            for (int rb = 0; rb < 2; ++rb)
                #pragma unroll
                for (int cb = 0; cb < 2; ++cb)
                    acc2[rb][cb] = __builtin_amdgcn_mfma_f32_16x16x32_bf16(w3f[ks][cb], hb[rb], acc2[rb][cb], 0, 0, 0);
            __builtin_amdgcn_s_setprio(0);
        }

        // ---- h3 = relu(acc2+b3); per-lane w4 partial -> padded LDS (no shfl) ----
        {
            f32x4 b3v0 = *reinterpret_cast<const f32x4*>(&sf_b3[cgrp * 32 + l4 * 4]);
            f32x4 b3v1 = *reinterpret_cast<const f32x4*>(&sf_b3[cgrp * 32 + 16 + l4 * 4]);
            f32x4 w4v0 = *reinterpret_cast<const f32x4*>(&sf_w4[cgrp * 32 + l4 * 4]);
            f32x4 w4v1 = *reinterpret_cast<const f32x4*>(&sf_w4[cgrp * 32 + 16 + l4 * 4]);
            #pragma unroll
            for (int rb = 0; rb < 2; ++rb) {
                float p = 0.f;
                #pragma unroll
                for (int i = 0; i < 4; ++i) {
                    float v0 = acc2[rb][0][i] + b3v0[i];
                    float v1 = acc2[rb][1][i] + b3v1[i];
                    v0 = v0 > 0.f ? v0 : 0.f;
                    v1 = v1 > 0.f ? v1 : 0.f;
                    p = fmaf(v0, w4v0[i], p);
                    p = fmaf(v1, w4v1[i], p);
                }
                partials[rhalf * 32 + rb * 16 + l15][cgrp * 4 + l4] = p;
            }
        }
        __syncthreads();   // partials + h2-read-complete

        // ---- final: wave 0 reduces 16 k-groups, sigmoid, store (overlaps
        //      next iteration's GEMM1 for waves 1..7) ----
        if (tid < 64) {
            const f32x4* pr = reinterpret_cast<const f32x4*>(&partials[tid][0]);
            f32x4 s0 = pr[0], s1 = pr[1], s2 = pr[2], s3 = pr[3];
            f32x4 ss = s0 + s1 + s2 + s3;
            float s = ss[0] + ss[1] + ss[2] + ss[3] + b4v;
            out[b * GG + t * 64 + tid] = 1.f / (1.f + __expf(-s));
        }
    }
}

// ---------------------------------------------------------------------------
extern "C" void kernel_launch(void* const* d_in, const int* in_sizes, int n_in,
                              void* d_out, int out_size, void* d_ws, size_t ws_size,
                              hipStream_t stream)
{
    const float* features = (const float*)d_in[0];
    const float* coords   = (const float*)d_in[1];
    const float* ce_w1 = (const float*)d_in[2];
    const float* ce_b1 = (const float*)d_in[3];
    const float* ce_w2 = (const float*)d_in[4];
    const float* ce_b2 = (const float*)d_in[5];
    const float* ce_w3 = (const float*)d_in[6];
    const float* ce_b3 = (const float*)d_in[7];
    const float* sf_w1 = (const float*)d_in[8];
    const float* sf_b1 = (const float*)d_in[9];
    const float* sf_w2 = (const float*)d_in[10];
    const float* sf_b2 = (const float*)d_in[11];
    const float* sf_w3 = (const float*)d_in[12];
    const float* sf_b3 = (const float*)d_in[13];
    const float* sf_w4 = (const float*)d_in[14];
    const float* sf_b4 = (const float*)d_in[15];
    float* out = (float*)d_out;

    char* ws = (char*)d_ws;
    float*  zpart = (float*)ws;                                  // 256 KB
    bf16_t* w2t   = (bf16_t*)(ws + 65536 * 4);                   // 128 KB
    bf16_t* w3t   = (bf16_t*)(ws + 65536 * 4 + 65536 * 2);       //  64 KB
    float*  w1t   = (float*)(ws + 65536 * 4 + 65536 * 2 + 32768 * 2); // 1 MB (optional)
    const size_t need_w1t = (size_t)(65536 * 4 + 65536 * 2 + 32768 * 2) + (size_t)FD * HD * 4;
    float* w1t_ptr = (ws_size >= need_w1t) ? w1t : nullptr;

    hipLaunchKernelGGL(prep_kernel, dim3(1024), dim3(256), 0, stream,
                       ce_w1, sf_w2, sf_w3, w1t_ptr, w2t, w3t);
    hipLaunchKernelGGL(ce_kernel, dim3(256), dim3(256), 0, stream,
                       features, ce_w1, w1t_ptr, ce_b1, ce_w2, ce_b2, ce_w3, ce_b3,
                       sf_w1, sf_b1, zpart);
    hipLaunchKernelGGL(field_kernel, dim3(256), dim3(512), 0, stream,
                       coords, sf_w1, zpart, w2t, sf_b2, w3t, sf_b3, sf_w4, sf_b4, out);
}